// Round 8
// baseline (197.550 us; speedup 1.0000x reference)
//
#include <hip/hip_runtime.h>
#include <math.h>

// Problem constants
#define B_   8
#define C_   64
#define H_   128
#define W_   128
#define HW_  16384
#define K2_  9

typedef float f32x4 __attribute__((ext_vector_type(4)));
typedef short bf16x8 __attribute__((ext_vector_type(8)));
typedef unsigned short u16x4 __attribute__((ext_vector_type(4)));
typedef unsigned int u32x4 __attribute__((ext_vector_type(4)));

// Workspace layout (float offsets):
//   wrP  deform A-frags bf16    @ 8192
//   wrP2 offmod A-frags bf16    @ 26624
//   xt   [B][H][W][64] bf16     @ 45056
#define WS_WRP  8192
#define WS_WRP2 26624
#define WS_XT   45056

static __device__ __forceinline__ unsigned short f2bf(float x) {
    unsigned int u = __float_as_uint(x);
    unsigned int r = (u + 0x7fffu + ((u >> 16) & 1u)) >> 16;   // RNE
    return (unsigned short)r;
}
static __device__ __forceinline__ float bf2f(unsigned short u) {
    return __uint_as_float(((unsigned int)u) << 16);
}
// packed f32x2 -> bf16x2 (RNE), single instruction on gfx950
static __device__ __forceinline__ unsigned int cvt_pk_bf16(float lo, float hi) {
    unsigned int r;
    asm("v_cvt_pk_bf16_f32 %0, %1, %2" : "=v"(r) : "v"(lo), "v"(hi));
    return r;
}
// element-wise register select (compiles to v_cndmask; no control flow)
static __device__ __forceinline__ u32x4 sel4(bool c, u32x4 a, u32x4 b) {
    u32x4 r;
    r[0] = c ? a[0] : b[0];
    r[1] = c ? a[1] : b[1];
    r[2] = c ? a[2] : b[2];
    r[3] = c ? a[3] : b[3];
    return r;
}

// ---------------------------------------------------------------------------
// Kernel 1: 1x1 fuse conv as bf16 MFMA GEMM (byte-identical to passing r7)
// ---------------------------------------------------------------------------
__global__ __launch_bounds__(256) void k_fuse(const float* __restrict__ xi,
                                              const float* __restrict__ xc,
                                              const float* __restrict__ wf,
                                              const float* __restrict__ wreg,
                                              const float* __restrict__ wOff,
                                              const float* __restrict__ wMod,
                                              unsigned short* __restrict__ xtb,
                                              unsigned short* __restrict__ wrP,
                                              unsigned short* __restrict__ wrP2) {
    __shared__ unsigned short sA[1024 * 8];   // 16 KB: [f=kc*4+mt][lane][8]
    const int t = threadIdx.x;
    const int lane = t & 63;
    const int wv = t >> 6;
    const int b = blockIdx.x & 7;
    const int yh = blockIdx.x >> 3;
    const int y = yh >> 1;
    const int h = yh & 1;

    // ---- pack wrP / wrP2 (blocks 0..17 only; consumed by later kernels) ----
    if (blockIdx.x < 18) {
        const int idx = blockIdx.x * 256 + t;
        if (idx < 4608) {
            int ln = idx & 63, mt = (idx >> 6) & 3, kc = (idx >> 8) & 1, tap = idx >> 9;
            int o = mt * 16 + (ln & 15);
            int ibase = kc * 32 + (ln >> 4) * 8;
#pragma unroll
            for (int j = 0; j < 8; ++j)
                wrP[idx * 8 + j] = f2bf(wreg[(o * 64 + ibase + j) * 9 + tap]);
        }
        if (idx < 2304) {
            int ln = idx & 63, mt = (idx >> 6) & 1, kc = idx >> 7;
            int m = mt * 16 + (ln & 15);
            int gkb = kc * 32 + (ln >> 4) * 8;
#pragma unroll
            for (int j = 0; j < 8; ++j) {
                int gk = gkb + j, tap = gk >> 6, ci = gk & 63;
                float v = 0.f;
                if (m < 18)      v = wOff[(m * 64 + ci) * 9 + tap];
                else if (m < 27) v = wMod[((m - 18) * 64 + ci) * 9 + tap];
                wrP2[idx * 8 + j] = f2bf(v);
            }
        }
    }

    // ---- build fuse A-frags in LDS (each block; 32 f2bf8-chunks /thread/4) --
#pragma unroll
    for (int r = 0; r < 4; ++r) {
        const int c = t + 256 * r;      // chunk 0..1023
        const int f = c >> 6;           // f = kc*4 + mt
        const int ln = c & 63;
        const int mt = f & 3, kc = f >> 2;
        const int m = mt * 16 + (ln & 15);
        const int kb = kc * 32 + (ln >> 4) * 8;
        const float* s = wf + m * 128 + kb;
        unsigned short us[8];
#pragma unroll
        for (int j = 0; j < 8; ++j) us[j] = f2bf(s[j]);
        *(bf16x8*)&sA[c * 8] = *(const bf16x8*)us;
    }
    __syncthreads();

    const int n15 = lane & 15;
    const int q4 = lane >> 4;
    const int px = h * 64 + wv * 16 + n15;
    const size_t poff = (size_t)y * W_ + px;

    f32x4 acc[4];
#pragma unroll
    for (int mt = 0; mt < 4; ++mt) acc[mt] = (f32x4){0.f, 0.f, 0.f, 0.f};

#pragma unroll
    for (int kc = 0; kc < 4; ++kc) {
        const float* src = (kc < 2)
            ? (xi + ((size_t)(b * 64 + kc * 32 + q4 * 8)) * HW_ + poff)
            : (xc + ((size_t)(b * 64 + (kc - 2) * 32 + q4 * 8)) * HW_ + poff);
        unsigned short us[8];
#pragma unroll
        for (int j = 0; j < 8; ++j) us[j] = f2bf(src[(size_t)j * HW_]);
        const bf16x8 bf = *(const bf16x8*)us;
#pragma unroll
        for (int mt = 0; mt < 4; ++mt) {
            const bf16x8 a = *(const bf16x8*)&sA[((kc * 4 + mt) * 64 + lane) * 8];
            acc[mt] = __builtin_amdgcn_mfma_f32_16x16x32_bf16(a, bf, acc[mt], 0, 0, 0);
        }
    }

#pragma unroll
    for (int mt = 0; mt < 4; ++mt) {
        u16x4 o4;
        o4.x = f2bf(acc[mt][0]); o4.y = f2bf(acc[mt][1]);
        o4.z = f2bf(acc[mt][2]); o4.w = f2bf(acc[mt][3]);
        *(u16x4*)&xtb[((size_t)b * HW_ + poff) * 64 + mt * 16 + q4 * 4] = o4;
    }
}

// ---------------------------------------------------------------------------
// Kernel 2 (fused offmod + deform), built ON TOP of the r7-passing k_deform:
//   - identical 5x68x72 window staging, identical (proven) gather constructs
//   - Phase 1 inserted before sampling: 3x3 off/mod conv GEMM reading the
//     same window (indices == old k_offmod: row+1, col+1) -> dy/dx/mod (f32,
//     bit-identical math) into LDS omS; __syncthreads(); sampling reads omv
//     from omS instead of global om.
//   Deletes the k_offmod dispatch and all om global traffic.
//   LDS: 48960 + 6912 = 55872 B -> 2 blocks/CU.
// ---------------------------------------------------------------------------
__global__ __launch_bounds__(256) void k_od(const unsigned short* __restrict__ xtb,
                                            const unsigned short* __restrict__ wrP2,
                                            const unsigned short* __restrict__ wrP,
                                            const float* __restrict__ bOff,
                                            const float* __restrict__ bMod,
                                            float* __restrict__ out) {
    __shared__ __align__(16) unsigned short sW[5 * 68 * 72];  // 48960 B
    __shared__ float omS[4][27][16];                          // 6912 B
    const int t = threadIdx.x;
    const int lane = t & 63;
    const int wv = t >> 6;
    const int b = blockIdx.x & 7;
    const int yh = blockIdx.x >> 3;
    const int y = yh >> 1;
    const int h = yh & 1;
    const int wx0 = h * 64 - 2;   // window px origin
    const int ylo = y - 2;        // window row origin

    // ---- stage 5x68 window (coalesced global reads, aligned b128 writes) --
    for (int i = t; i < 2720; i += 256) {
        const int c8 = i & 7;
        const int p  = (i >> 3) % 68;
        const int r  = (i >> 3) / 68;
        const int gx = wx0 + p;
        const int gy = ylo + r;
        bf16x8 v = {0, 0, 0, 0, 0, 0, 0, 0};
        if (gx >= 0 && gx < W_ && gy >= 0 && gy < H_)
            v = *(const bf16x8*)&xtb[(((size_t)(b * H_ + gy)) * W_ + gx) * 64 + c8 * 8];
        *(bf16x8*)&sW[(r * 68 + p) * 72 + c8 * 8] = v;
    }
    __syncthreads();

    const int n15 = lane & 15;
    const int q4 = lane >> 4;
    const int px = h * 64 + wv * 16 + n15;

    // ---- Phase 1: 3x3 off/mod conv GEMM from the window ----
    {
        f32x4 accO[2];
        accO[0] = (f32x4){0.f, 0.f, 0.f, 0.f};
        accO[1] = (f32x4){0.f, 0.f, 0.f, 0.f};
#pragma unroll
        for (int kc = 0; kc < 18; ++kc) {
            const int gkb = kc * 32 + q4 * 8;
            const int tap = gkb >> 6;
            const int ci = gkb & 63;
            const int row = tap / 3, kx = tap % 3;
            // input pixel gx = px + kx - 1 -> window col = wv*16+n15+kx+1
            const bf16x8 bf = *(const bf16x8*)
                &sW[((row + 1) * 68 + (wv * 16 + n15 + kx + 1)) * 72 + ci];
            const bf16x8 a0 = *(const bf16x8*)(wrP2 + (((size_t)(kc * 2 + 0) * 64 + lane) * 8));
            const bf16x8 a1 = *(const bf16x8*)(wrP2 + (((size_t)(kc * 2 + 1) * 64 + lane) * 8));
            accO[0] = __builtin_amdgcn_mfma_f32_16x16x32_bf16(a0, bf, accO[0], 0, 0, 0);
            accO[1] = __builtin_amdgcn_mfma_f32_16x16x32_bf16(a1, bf, accO[1], 0, 0, 0);
        }
#pragma unroll
        for (int mt = 0; mt < 2; ++mt)
#pragma unroll
            for (int r = 0; r < 4; ++r) {
                const int o = mt * 16 + q4 * 4 + r;
                if (o < 18) {
                    const int c = (o >> 1) + ((o & 1) ? 9 : 0);
                    omS[wv][c][n15] = accO[mt][r] + bOff[o];
                } else if (o < 27) {
                    const float z = accO[mt][r] + bMod[o - 18];
                    omS[wv][o][n15] = 2.f / (1.f + __expf(-z));
                }
            }
    }
    __syncthreads();

    // ---- Phase 2: deformable sampling (r7-proven constructs, omv from LDS) --
    const char* xbB = (const char*)(xtb + (size_t)b * HW_ * 64);

    float omv[27];
#pragma unroll
    for (int i = 0; i < 27; ++i) omv[i] = omS[wv][i][n15];

    f32x4 acc[4];
#pragma unroll
    for (int mt = 0; mt < 4; ++mt) acc[mt] = (f32x4){0.f, 0.f, 0.f, 0.f};

    for (int k = 0; k < 9; ++k) {
        const int ky = k / 3 - 1, kx = k % 3 - 1;
        const float dy  = omv[k];
        const float dxv = omv[9 + k];
        const float m   = omv[18 + k];
        const float py  = (float)(y + ky) + dy;
        const float pxe = (float)(px + kx) + dxv;
        const float y0f = floorf(py), x0f = floorf(pxe);
        const int y0i = (int)y0f, x0i = (int)x0f;
        const float wy1 = py - y0f, wx1 = pxe - x0f;
        const float wy0 = 1.f - wy1, wx0f = 1.f - wx1;

        u32x4 gv[8];
        float wts[4];
#pragma unroll
        for (int c = 0; c < 4; ++c) {
            const int cy = c >> 1, cx = c & 1;
            const int yy = y0i + cy;
            const int xx = x0i + cx;
            const bool ok = (yy >= 0) && (yy < H_) && (xx >= 0) && (xx < W_);
            wts[c] = ok ? (cy ? wy1 : wy0) * (cx ? wx1 : wx0f) * m : 0.f;
            const bool inw = (yy >= ylo) && (yy <= ylo + 4)
                          && (xx >= wx0) && (xx < wx0 + 68);
            // clamped window coords: LDS address always valid & staged
            int wr = yy - ylo; wr = min(max(wr, 0), 4);
            int wc = xx - wx0; wc = min(max(wc, 0), 67);
            const int lsW = (wr * 68 + wc) * 72 + q4 * 8;
            const bf16x8 l0 = *(const bf16x8*)&sW[lsW];
            const bf16x8 l1 = *(const bf16x8*)&sW[lsW + 32];
            // clamped global address; in-window lanes fold to record 0 (L1-hot)
            const int yc = min(max(yy, 0), H_ - 1);
            const int xc = min(max(xx, 0), W_ - 1);
            const int off = inw ? (q4 * 16) : ((yc * W_ + xc) * 128 + q4 * 16);
            const bf16x8 g0 = *(const bf16x8*)(xbB + off);
            const bf16x8 g1 = *(const bf16x8*)(xbB + off + 64);
            u32x4 lu0, lu1, gu0, gu1;
            __builtin_memcpy(&lu0, &l0, 16);
            __builtin_memcpy(&lu1, &l1, 16);
            __builtin_memcpy(&gu0, &g0, 16);
            __builtin_memcpy(&gu1, &g1, 16);
            gv[c]     = sel4(inw, lu0, gu0);
            gv[4 + c] = sel4(inw, lu1, gu1);
        }

        const float w0 = wts[0], w1 = wts[1], w2 = wts[2], w3 = wts[3];
#pragma unroll
        for (int kc = 0; kc < 2; ++kc) {
            unsigned int outw[4];
#pragma unroll
            for (int d = 0; d < 4; ++d) {
                const unsigned int av = gv[kc * 4 + 0][d];
                const unsigned int bv = gv[kc * 4 + 1][d];
                const unsigned int cv = gv[kc * 4 + 2][d];
                const unsigned int ev = gv[kc * 4 + 3][d];
                const float lo = __uint_as_float(av << 16) * w0
                               + __uint_as_float(bv << 16) * w1
                               + __uint_as_float(cv << 16) * w2
                               + __uint_as_float(ev << 16) * w3;
                const float hi = __uint_as_float(av & 0xffff0000u) * w0
                               + __uint_as_float(bv & 0xffff0000u) * w1
                               + __uint_as_float(cv & 0xffff0000u) * w2
                               + __uint_as_float(ev & 0xffff0000u) * w3;
                outw[d] = cvt_pk_bf16(lo, hi);
            }
            const bf16x8 bfB = *(const bf16x8*)outw;
#pragma unroll
            for (int mt = 0; mt < 4; ++mt) {
                const bf16x8 a = *(const bf16x8*)(wrP +
                    ((((size_t)((k * 2 + kc) * 4 + mt)) * 64 + lane) * 8));
                acc[mt] = __builtin_amdgcn_mfma_f32_16x16x32_bf16(a, bfB, acc[mt], 0, 0, 0);
            }
        }
    }

    // epilogue: D[o = mt*16 + q4*4 + r][px], out NCHW
#pragma unroll
    for (int mt = 0; mt < 4; ++mt)
#pragma unroll
        for (int r = 0; r < 4; ++r) {
            const int o = mt * 16 + q4 * 4 + r;
            out[(((size_t)(b * 64 + o)) * H_ + y) * W_ + px] = acc[mt][r];
        }
}

// ---------------------------------------------------------------------------
extern "C" void kernel_launch(void* const* d_in, const int* in_sizes, int n_in,
                              void* d_out, int out_size, void* d_ws, size_t ws_size,
                              hipStream_t stream) {
    const float* x_img  = (const float*)d_in[0];
    const float* x_cont = (const float*)d_in[1];
    const float* w_fuse = (const float*)d_in[2];
    const float* w_off  = (const float*)d_in[3];
    const float* b_off  = (const float*)d_in[4];
    const float* w_mod  = (const float*)d_in[5];
    const float* b_mod  = (const float*)d_in[6];
    const float* w_reg  = (const float*)d_in[7];
    float* out = (float*)d_out;

    float* ws  = (float*)d_ws;
    unsigned short* wrP  = (unsigned short*)(ws + WS_WRP);
    unsigned short* wrP2 = (unsigned short*)(ws + WS_WRP2);
    unsigned short* xtb  = (unsigned short*)(ws + WS_XT);

    k_fuse<<<B_ * H_ * 2, 256, 0, stream>>>(x_img, x_cont, w_fuse, w_reg, w_off,
                                            w_mod, xtb, wrP, wrP2);
    k_od<<<B_ * H_ * 2, 256, 0, stream>>>(xtb, wrP2, wrP, b_off, b_mod, out);
}

// Round 9
// 186.659 us; speedup vs baseline: 1.0583x; 1.0583x over previous
//
#include <hip/hip_runtime.h>
#include <math.h>

// Problem constants
#define B_   8
#define C_   64
#define H_   128
#define W_   128
#define HW_  16384
#define K2_  9

typedef float f32x4 __attribute__((ext_vector_type(4)));
typedef short bf16x8 __attribute__((ext_vector_type(8)));
typedef unsigned short u16x4 __attribute__((ext_vector_type(4)));
typedef unsigned int u32x4 __attribute__((ext_vector_type(4)));

// Workspace layout (float offsets):
//   wrP  deform A-frags bf16    @ 8192
//   wrP2 offmod A-frags bf16    @ 26624
//   xt   [B][H][W][64] bf16     @ 45056
#define WS_WRP  8192
#define WS_WRP2 26624
#define WS_XT   45056

static __device__ __forceinline__ unsigned short f2bf(float x) {
    unsigned int u = __float_as_uint(x);
    unsigned int r = (u + 0x7fffu + ((u >> 16) & 1u)) >> 16;   // RNE
    return (unsigned short)r;
}
static __device__ __forceinline__ float bf2f(unsigned short u) {
    return __uint_as_float(((unsigned int)u) << 16);
}
// packed f32x2 -> bf16x2 (RNE), single instruction on gfx950
static __device__ __forceinline__ unsigned int cvt_pk_bf16(float lo, float hi) {
    unsigned int r;
    asm("v_cvt_pk_bf16_f32 %0, %1, %2" : "=v"(r) : "v"(lo), "v"(hi));
    return r;
}
// element-wise register select (compiles to v_cndmask; no control flow)
static __device__ __forceinline__ u32x4 sel4(bool c, u32x4 a, u32x4 b) {
    u32x4 r;
    r[0] = c ? a[0] : b[0];
    r[1] = c ? a[1] : b[1];
    r[2] = c ? a[2] : b[2];
    r[3] = c ? a[3] : b[3];
    return r;
}

// ---------------------------------------------------------------------------
// Kernel 1: 1x1 fuse conv as bf16 MFMA GEMM (byte-identical to passing r8)
// ---------------------------------------------------------------------------
__global__ __launch_bounds__(256) void k_fuse(const float* __restrict__ xi,
                                              const float* __restrict__ xc,
                                              const float* __restrict__ wf,
                                              const float* __restrict__ wreg,
                                              const float* __restrict__ wOff,
                                              const float* __restrict__ wMod,
                                              unsigned short* __restrict__ xtb,
                                              unsigned short* __restrict__ wrP,
                                              unsigned short* __restrict__ wrP2) {
    __shared__ unsigned short sA[1024 * 8];   // 16 KB: [f=kc*4+mt][lane][8]
    const int t = threadIdx.x;
    const int lane = t & 63;
    const int wv = t >> 6;
    const int b = blockIdx.x & 7;
    const int yh = blockIdx.x >> 3;
    const int y = yh >> 1;
    const int h = yh & 1;

    // ---- pack wrP / wrP2 (blocks 0..17 only; consumed by later kernels) ----
    if (blockIdx.x < 18) {
        const int idx = blockIdx.x * 256 + t;
        if (idx < 4608) {
            int ln = idx & 63, mt = (idx >> 6) & 3, kc = (idx >> 8) & 1, tap = idx >> 9;
            int o = mt * 16 + (ln & 15);
            int ibase = kc * 32 + (ln >> 4) * 8;
#pragma unroll
            for (int j = 0; j < 8; ++j)
                wrP[idx * 8 + j] = f2bf(wreg[(o * 64 + ibase + j) * 9 + tap]);
        }
        if (idx < 2304) {
            int ln = idx & 63, mt = (idx >> 6) & 1, kc = idx >> 7;
            int m = mt * 16 + (ln & 15);
            int gkb = kc * 32 + (ln >> 4) * 8;
#pragma unroll
            for (int j = 0; j < 8; ++j) {
                int gk = gkb + j, tap = gk >> 6, ci = gk & 63;
                float v = 0.f;
                if (m < 18)      v = wOff[(m * 64 + ci) * 9 + tap];
                else if (m < 27) v = wMod[((m - 18) * 64 + ci) * 9 + tap];
                wrP2[idx * 8 + j] = f2bf(v);
            }
        }
    }

    // ---- build fuse A-frags in LDS (each block; 32 f2bf8-chunks /thread/4) --
#pragma unroll
    for (int r = 0; r < 4; ++r) {
        const int c = t + 256 * r;      // chunk 0..1023
        const int f = c >> 6;           // f = kc*4 + mt
        const int ln = c & 63;
        const int mt = f & 3, kc = f >> 2;
        const int m = mt * 16 + (ln & 15);
        const int kb = kc * 32 + (ln >> 4) * 8;
        const float* s = wf + m * 128 + kb;
        unsigned short us[8];
#pragma unroll
        for (int j = 0; j < 8; ++j) us[j] = f2bf(s[j]);
        *(bf16x8*)&sA[c * 8] = *(const bf16x8*)us;
    }
    __syncthreads();

    const int n15 = lane & 15;
    const int q4 = lane >> 4;
    const int px = h * 64 + wv * 16 + n15;
    const size_t poff = (size_t)y * W_ + px;

    f32x4 acc[4];
#pragma unroll
    for (int mt = 0; mt < 4; ++mt) acc[mt] = (f32x4){0.f, 0.f, 0.f, 0.f};

#pragma unroll
    for (int kc = 0; kc < 4; ++kc) {
        const float* src = (kc < 2)
            ? (xi + ((size_t)(b * 64 + kc * 32 + q4 * 8)) * HW_ + poff)
            : (xc + ((size_t)(b * 64 + (kc - 2) * 32 + q4 * 8)) * HW_ + poff);
        unsigned short us[8];
#pragma unroll
        for (int j = 0; j < 8; ++j) us[j] = f2bf(src[(size_t)j * HW_]);
        const bf16x8 bf = *(const bf16x8*)us;
#pragma unroll
        for (int mt = 0; mt < 4; ++mt) {
            const bf16x8 a = *(const bf16x8*)&sA[((kc * 4 + mt) * 64 + lane) * 8];
            acc[mt] = __builtin_amdgcn_mfma_f32_16x16x32_bf16(a, bf, acc[mt], 0, 0, 0);
        }
    }

#pragma unroll
    for (int mt = 0; mt < 4; ++mt) {
        u16x4 o4;
        o4.x = f2bf(acc[mt][0]); o4.y = f2bf(acc[mt][1]);
        o4.z = f2bf(acc[mt][2]); o4.w = f2bf(acc[mt][3]);
        *(u16x4*)&xtb[((size_t)b * HW_ + poff) * 64 + mt * 16 + q4 * 4] = o4;
    }
}

// ---------------------------------------------------------------------------
// Kernel 2 (fused offmod + deform).  vs r8: Phase-2 corner gather gains a
// WAVE-UNIFORM fast path — when every lane's tap is fully in-window
// ((unsigned)(y0i-ylo)<=3 && (unsigned)(x0i-wx0)<=66, one check for all 4
// corners), gather = 8 ds_read_b128 off one base with compile-time corner
// offsets (+72, +4896, +4968 shorts); no global loads, no cndmask selects,
// no clamps.  Slow path = byte-identical r7/r8 proven constructs.
// Out-of-image corners in fast path read staged zeros -> contribution 0,
// numerically identical.  LDS: 48960 + 6912 = 55872 B -> 2 blocks/CU.
// ---------------------------------------------------------------------------
__global__ __launch_bounds__(256) void k_od(const unsigned short* __restrict__ xtb,
                                            const unsigned short* __restrict__ wrP2,
                                            const unsigned short* __restrict__ wrP,
                                            const float* __restrict__ bOff,
                                            const float* __restrict__ bMod,
                                            float* __restrict__ out) {
    __shared__ __align__(16) unsigned short sW[5 * 68 * 72];  // 48960 B
    __shared__ float omS[4][27][16];                          // 6912 B
    const int t = threadIdx.x;
    const int lane = t & 63;
    const int wv = t >> 6;
    const int b = blockIdx.x & 7;
    const int yh = blockIdx.x >> 3;
    const int y = yh >> 1;
    const int h = yh & 1;
    const int wx0 = h * 64 - 2;   // window px origin
    const int ylo = y - 2;        // window row origin

    // ---- stage 5x68 window (coalesced global reads, aligned b128 writes) --
    for (int i = t; i < 2720; i += 256) {
        const int c8 = i & 7;
        const int p  = (i >> 3) % 68;
        const int r  = (i >> 3) / 68;
        const int gx = wx0 + p;
        const int gy = ylo + r;
        bf16x8 v = {0, 0, 0, 0, 0, 0, 0, 0};
        if (gx >= 0 && gx < W_ && gy >= 0 && gy < H_)
            v = *(const bf16x8*)&xtb[(((size_t)(b * H_ + gy)) * W_ + gx) * 64 + c8 * 8];
        *(bf16x8*)&sW[(r * 68 + p) * 72 + c8 * 8] = v;
    }
    __syncthreads();

    const int n15 = lane & 15;
    const int q4 = lane >> 4;
    const int px = h * 64 + wv * 16 + n15;

    // ---- Phase 1: 3x3 off/mod conv GEMM from the window ----
    {
        f32x4 accO[2];
        accO[0] = (f32x4){0.f, 0.f, 0.f, 0.f};
        accO[1] = (f32x4){0.f, 0.f, 0.f, 0.f};
#pragma unroll
        for (int kc = 0; kc < 18; ++kc) {
            const int gkb = kc * 32 + q4 * 8;
            const int tap = gkb >> 6;
            const int ci = gkb & 63;
            const int row = tap / 3, kx = tap % 3;
            const bf16x8 bf = *(const bf16x8*)
                &sW[((row + 1) * 68 + (wv * 16 + n15 + kx + 1)) * 72 + ci];
            const bf16x8 a0 = *(const bf16x8*)(wrP2 + (((size_t)(kc * 2 + 0) * 64 + lane) * 8));
            const bf16x8 a1 = *(const bf16x8*)(wrP2 + (((size_t)(kc * 2 + 1) * 64 + lane) * 8));
            accO[0] = __builtin_amdgcn_mfma_f32_16x16x32_bf16(a0, bf, accO[0], 0, 0, 0);
            accO[1] = __builtin_amdgcn_mfma_f32_16x16x32_bf16(a1, bf, accO[1], 0, 0, 0);
        }
#pragma unroll
        for (int mt = 0; mt < 2; ++mt)
#pragma unroll
            for (int r = 0; r < 4; ++r) {
                const int o = mt * 16 + q4 * 4 + r;
                if (o < 18) {
                    const int c = (o >> 1) + ((o & 1) ? 9 : 0);
                    omS[wv][c][n15] = accO[mt][r] + bOff[o];
                } else if (o < 27) {
                    const float z = accO[mt][r] + bMod[o - 18];
                    omS[wv][o][n15] = 2.f / (1.f + __expf(-z));
                }
            }
    }
    __syncthreads();

    // ---- Phase 2: deformable sampling + MFMA einsum ----
    const char* xbB = (const char*)(xtb + (size_t)b * HW_ * 64);

    float omv[27];
#pragma unroll
    for (int i = 0; i < 27; ++i) omv[i] = omS[wv][i][n15];

    f32x4 acc[4];
#pragma unroll
    for (int mt = 0; mt < 4; ++mt) acc[mt] = (f32x4){0.f, 0.f, 0.f, 0.f};

    for (int k = 0; k < 9; ++k) {
        const int ky = k / 3 - 1, kx = k % 3 - 1;
        const float dy  = omv[k];
        const float dxv = omv[9 + k];
        const float m   = omv[18 + k];
        const float py  = (float)(y + ky) + dy;
        const float pxe = (float)(px + kx) + dxv;
        const float y0f = floorf(py), x0f = floorf(pxe);
        const int y0i = (int)y0f, x0i = (int)x0f;
        const float wy1 = py - y0f, wx1 = pxe - x0f;
        const float wy0 = 1.f - wy1, wx0f = 1.f - wx1;

        // ---- shared per-corner weights (identical numerics both paths) ----
        float wts[4];
#pragma unroll
        for (int c = 0; c < 4; ++c) {
            const int cy = c >> 1, cx = c & 1;
            const int yy = y0i + cy;
            const int xx = x0i + cx;
            const bool ok = (yy >= 0) && (yy < H_) && (xx >= 0) && (xx < W_);
            wts[c] = ok ? (cy ? wy1 : wy0) * (cx ? wx1 : wx0f) * m : 0.f;
        }

        // all-4-corners-in-window collapses to one check on the (y0,x0) corner
        const int wr0 = y0i - ylo;
        const int wc0 = x0i - wx0;
        const bool fast = ((unsigned)wr0 <= 3u) && ((unsigned)wc0 <= 66u);

        u32x4 gv[8];
        if (__all(fast)) {
            // ---- fast path: pure LDS, one base + immediate corner offsets --
            const int base = (wr0 * 68 + wc0) * 72 + q4 * 8;
            const bf16x8 l00 = *(const bf16x8*)&sW[base];               // (0,0) lo
            const bf16x8 h00 = *(const bf16x8*)&sW[base + 32];          // (0,0) hi
            const bf16x8 l01 = *(const bf16x8*)&sW[base + 72];          // (0,1)
            const bf16x8 h01 = *(const bf16x8*)&sW[base + 72 + 32];
            const bf16x8 l10 = *(const bf16x8*)&sW[base + 4896];        // (1,0)
            const bf16x8 h10 = *(const bf16x8*)&sW[base + 4896 + 32];
            const bf16x8 l11 = *(const bf16x8*)&sW[base + 4968];        // (1,1)
            const bf16x8 h11 = *(const bf16x8*)&sW[base + 4968 + 32];
            __builtin_memcpy(&gv[0], &l00, 16);
            __builtin_memcpy(&gv[1], &l01, 16);
            __builtin_memcpy(&gv[2], &l10, 16);
            __builtin_memcpy(&gv[3], &l11, 16);
            __builtin_memcpy(&gv[4], &h00, 16);
            __builtin_memcpy(&gv[5], &h01, 16);
            __builtin_memcpy(&gv[6], &h10, 16);
            __builtin_memcpy(&gv[7], &h11, 16);
        } else {
            // ---- slow path: byte-identical r7/r8 proven constructs --------
#pragma unroll
            for (int c = 0; c < 4; ++c) {
                const int cy = c >> 1, cx = c & 1;
                const int yy = y0i + cy;
                const int xx = x0i + cx;
                const bool inw = (yy >= ylo) && (yy <= ylo + 4)
                              && (xx >= wx0) && (xx < wx0 + 68);
                int wr = yy - ylo; wr = min(max(wr, 0), 4);
                int wc = xx - wx0; wc = min(max(wc, 0), 67);
                const int lsW = (wr * 68 + wc) * 72 + q4 * 8;
                const bf16x8 l0 = *(const bf16x8*)&sW[lsW];
                const bf16x8 l1 = *(const bf16x8*)&sW[lsW + 32];
                const int yc = min(max(yy, 0), H_ - 1);
                const int xc = min(max(xx, 0), W_ - 1);
                const int off = inw ? (q4 * 16) : ((yc * W_ + xc) * 128 + q4 * 16);
                const bf16x8 g0 = *(const bf16x8*)(xbB + off);
                const bf16x8 g1 = *(const bf16x8*)(xbB + off + 64);
                u32x4 lu0, lu1, gu0, gu1;
                __builtin_memcpy(&lu0, &l0, 16);
                __builtin_memcpy(&lu1, &l1, 16);
                __builtin_memcpy(&gu0, &g0, 16);
                __builtin_memcpy(&gu1, &g1, 16);
                gv[c]     = sel4(inw, lu0, gu0);
                gv[4 + c] = sel4(inw, lu1, gu1);
            }
        }

        const float w0 = wts[0], w1 = wts[1], w2 = wts[2], w3 = wts[3];
#pragma unroll
        for (int kc = 0; kc < 2; ++kc) {
            unsigned int outw[4];
#pragma unroll
            for (int d = 0; d < 4; ++d) {
                const unsigned int av = gv[kc * 4 + 0][d];
                const unsigned int bv = gv[kc * 4 + 1][d];
                const unsigned int cv = gv[kc * 4 + 2][d];
                const unsigned int ev = gv[kc * 4 + 3][d];
                const float lo = __uint_as_float(av << 16) * w0
                               + __uint_as_float(bv << 16) * w1
                               + __uint_as_float(cv << 16) * w2
                               + __uint_as_float(ev << 16) * w3;
                const float hi = __uint_as_float(av & 0xffff0000u) * w0
                               + __uint_as_float(bv & 0xffff0000u) * w1
                               + __uint_as_float(cv & 0xffff0000u) * w2
                               + __uint_as_float(ev & 0xffff0000u) * w3;
                outw[d] = cvt_pk_bf16(lo, hi);
            }
            const bf16x8 bfB = *(const bf16x8*)outw;
#pragma unroll
            for (int mt = 0; mt < 4; ++mt) {
                const bf16x8 a = *(const bf16x8*)(wrP +
                    ((((size_t)((k * 2 + kc) * 4 + mt)) * 64 + lane) * 8));
                acc[mt] = __builtin_amdgcn_mfma_f32_16x16x32_bf16(a, bfB, acc[mt], 0, 0, 0);
            }
        }
    }

    // epilogue: D[o = mt*16 + q4*4 + r][px], out NCHW
#pragma unroll
    for (int mt = 0; mt < 4; ++mt)
#pragma unroll
        for (int r = 0; r < 4; ++r) {
            const int o = mt * 16 + q4 * 4 + r;
            out[(((size_t)(b * 64 + o)) * H_ + y) * W_ + px] = acc[mt][r];
        }
}

// ---------------------------------------------------------------------------
extern "C" void kernel_launch(void* const* d_in, const int* in_sizes, int n_in,
                              void* d_out, int out_size, void* d_ws, size_t ws_size,
                              hipStream_t stream) {
    const float* x_img  = (const float*)d_in[0];
    const float* x_cont = (const float*)d_in[1];
    const float* w_fuse = (const float*)d_in[2];
    const float* w_off  = (const float*)d_in[3];
    const float* b_off  = (const float*)d_in[4];
    const float* w_mod  = (const float*)d_in[5];
    const float* b_mod  = (const float*)d_in[6];
    const float* w_reg  = (const float*)d_in[7];
    float* out = (float*)d_out;

    float* ws  = (float*)d_ws;
    unsigned short* wrP  = (unsigned short*)(ws + WS_WRP);
    unsigned short* wrP2 = (unsigned short*)(ws + WS_WRP2);
    unsigned short* xtb  = (unsigned short*)(ws + WS_XT);

    k_fuse<<<B_ * H_ * 2, 256, 0, stream>>>(x_img, x_cont, w_fuse, w_reg, w_off,
                                            w_mod, xtb, wrP, wrP2);
    k_od<<<B_ * H_ * 2, 256, 0, stream>>>(xtb, wrP2, wrP, b_off, b_mod, out);
}

// Round 10
// 183.926 us; speedup vs baseline: 1.0741x; 1.0149x over previous
//
#include <hip/hip_runtime.h>
#include <math.h>

// Problem constants
#define B_   8
#define C_   64
#define H_   128
#define W_   128
#define HW_  16384
#define K2_  9

typedef float f32x4 __attribute__((ext_vector_type(4)));
typedef short bf16x8 __attribute__((ext_vector_type(8)));
typedef unsigned short u16x4 __attribute__((ext_vector_type(4)));
typedef unsigned int u32x4 __attribute__((ext_vector_type(4)));
typedef unsigned int u32x2 __attribute__((ext_vector_type(2)));

// Workspace layout (float offsets):
//   wrP  deform A-frags bf16    @ 8192
//   wrP2 offmod A-frags bf16    @ 26624
//   xt   [B][H][W][64] bf16     @ 45056
#define WS_WRP  8192
#define WS_WRP2 26624
#define WS_XT   45056

static __device__ __forceinline__ unsigned short f2bf(float x) {
    unsigned int u = __float_as_uint(x);
    unsigned int r = (u + 0x7fffu + ((u >> 16) & 1u)) >> 16;   // RNE
    return (unsigned short)r;
}
static __device__ __forceinline__ float bf2f(unsigned short u) {
    return __uint_as_float(((unsigned int)u) << 16);
}
// packed f32x2 -> bf16x2 (RNE), single instruction on gfx950
static __device__ __forceinline__ unsigned int cvt_pk_bf16(float lo, float hi) {
    unsigned int r;
    asm("v_cvt_pk_bf16_f32 %0, %1, %2" : "=v"(r) : "v"(lo), "v"(hi));
    return r;
}
// element-wise register select (compiles to v_cndmask; no control flow)
static __device__ __forceinline__ u32x4 sel4(bool c, u32x4 a, u32x4 b) {
    u32x4 r;
    r[0] = c ? a[0] : b[0];
    r[1] = c ? a[1] : b[1];
    r[2] = c ? a[2] : b[2];
    r[3] = c ? a[3] : b[3];
    return r;
}

// ---------------------------------------------------------------------------
// Kernel 1: 1x1 fuse conv as bf16 MFMA GEMM.
// v2 B-path: coalesced float4 loads (8/thread, 4x256B dense per wave instr)
// + cvt_pk_bf16 packing + px-major->ch-major transpose via swizzled LDS tile
// sX[64 px][272 B] (col-XOR swizzle off^=((px>>3)&7)<<4: bijective per row,
// writes 2-way banked, b128 reads 2-way -- both free).  Replaces 32 strided
// scalar dword loads + 64 scalar f2bf per thread.  wrP/wrP2 packing and sA
// build unchanged (proven).
// ---------------------------------------------------------------------------
__global__ __launch_bounds__(256) void k_fuse(const float* __restrict__ xi,
                                              const float* __restrict__ xc,
                                              const float* __restrict__ wf,
                                              const float* __restrict__ wreg,
                                              const float* __restrict__ wOff,
                                              const float* __restrict__ wMod,
                                              unsigned short* __restrict__ xtb,
                                              unsigned short* __restrict__ wrP,
                                              unsigned short* __restrict__ wrP2) {
    __shared__ unsigned short sA[1024 * 8];          // 16 KB: [f=kc*4+mt][lane][8]
    __shared__ __align__(16) char sX[64 * 272];      // 17 KB: [px][136 shorts] swz
    const int t = threadIdx.x;
    const int lane = t & 63;
    const int wv = t >> 6;
    const int b = blockIdx.x & 7;
    const int yh = blockIdx.x >> 3;
    const int y = yh >> 1;
    const int h = yh & 1;

    // ---- pack wrP / wrP2 (blocks 0..17 only; consumed by later kernels) ----
    if (blockIdx.x < 18) {
        const int idx = blockIdx.x * 256 + t;
        if (idx < 4608) {
            int ln = idx & 63, mt = (idx >> 6) & 3, kc = (idx >> 8) & 1, tap = idx >> 9;
            int o = mt * 16 + (ln & 15);
            int ibase = kc * 32 + (ln >> 4) * 8;
#pragma unroll
            for (int j = 0; j < 8; ++j)
                wrP[idx * 8 + j] = f2bf(wreg[(o * 64 + ibase + j) * 9 + tap]);
        }
        if (idx < 2304) {
            int ln = idx & 63, mt = (idx >> 6) & 1, kc = idx >> 7;
            int m = mt * 16 + (ln & 15);
            int gkb = kc * 32 + (ln >> 4) * 8;
#pragma unroll
            for (int j = 0; j < 8; ++j) {
                int gk = gkb + j, tap = gk >> 6, ci = gk & 63;
                float v = 0.f;
                if (m < 18)      v = wOff[(m * 64 + ci) * 9 + tap];
                else if (m < 27) v = wMod[((m - 18) * 64 + ci) * 9 + tap];
                wrP2[idx * 8 + j] = f2bf(v);
            }
        }
    }

    // ---- build fuse A-frags in LDS (unchanged) ----
#pragma unroll
    for (int r = 0; r < 4; ++r) {
        const int c = t + 256 * r;      // chunk 0..1023
        const int f = c >> 6;           // f = kc*4 + mt
        const int ln = c & 63;
        const int mt = f & 3, kc = f >> 2;
        const int m = mt * 16 + (ln & 15);
        const int kb = kc * 32 + (ln >> 4) * 8;
        const float* s = wf + m * 128 + kb;
        unsigned short us[8];
#pragma unroll
        for (int j = 0; j < 8; ++j) us[j] = f2bf(s[j]);
        *(bf16x8*)&sA[c * 8] = *(const bf16x8*)us;
    }

    // ---- stage B tile: [64 px][128 ch] bf16, coalesced float4 + cvt_pk ----
    {
        const int pxq = t & 15;          // px quad (4 consecutive px)
        const int cp  = t >> 4;          // channel-pair base (0..15)
        const size_t goff = (size_t)y * W_ + h * 64 + pxq * 4;
#pragma unroll
        for (int i = 0; i < 4; ++i) {
            const int cpi = cp + 16 * i;     // channel pair 0..63
            const int ch0 = cpi * 2;         // even channel 0..126
            const float* p0 = (ch0 < 64)
                ? (xi + ((size_t)(b * 64 + ch0)) * HW_ + goff)
                : (xc + ((size_t)(b * 64 + ch0 - 64)) * HW_ + goff);
            const f32x4 f0 = *(const f32x4*)p0;            // ch0,  4 px
            const f32x4 f1 = *(const f32x4*)(p0 + HW_);    // ch0+1, 4 px
#pragma unroll
            for (int j = 0; j < 4; ++j) {
                const unsigned w = cvt_pk_bf16(f0[j], f1[j]);  // [ch0, ch0+1]
                const int px = pxq * 4 + j;
                *(unsigned*)(sX + px * 272 +
                             ((cpi * 4) ^ (((px >> 3) & 7) << 4))) = w;
            }
        }
    }
    __syncthreads();

    const int n15 = lane & 15;
    const int q4 = lane >> 4;
    const int pxl = wv * 16 + n15;
    const int px = h * 64 + pxl;
    const size_t poff = (size_t)y * W_ + px;

    f32x4 acc[4];
#pragma unroll
    for (int mt = 0; mt < 4; ++mt) acc[mt] = (f32x4){0.f, 0.f, 0.f, 0.f};

#pragma unroll
    for (int kc = 0; kc < 4; ++kc) {
        const int kb = kc * 32 + q4 * 8;
        const bf16x8 bf = *(const bf16x8*)(sX + pxl * 272 +
                              ((kb * 2) ^ (((pxl >> 3) & 7) << 4)));
#pragma unroll
        for (int mt = 0; mt < 4; ++mt) {
            const bf16x8 a = *(const bf16x8*)&sA[((kc * 4 + mt) * 64 + lane) * 8];
            acc[mt] = __builtin_amdgcn_mfma_f32_16x16x32_bf16(a, bf, acc[mt], 0, 0, 0);
        }
    }

#pragma unroll
    for (int mt = 0; mt < 4; ++mt) {
        u32x2 o2;
        o2[0] = cvt_pk_bf16(acc[mt][0], acc[mt][1]);
        o2[1] = cvt_pk_bf16(acc[mt][2], acc[mt][3]);
        *(u32x2*)&xtb[((size_t)b * HW_ + poff) * 64 + mt * 16 + q4 * 4] = o2;
    }
}

// ---------------------------------------------------------------------------
// Kernel 2 (fused offmod + deform) — byte-identical to passing r9.
// ---------------------------------------------------------------------------
__global__ __launch_bounds__(256) void k_od(const unsigned short* __restrict__ xtb,
                                            const unsigned short* __restrict__ wrP2,
                                            const unsigned short* __restrict__ wrP,
                                            const float* __restrict__ bOff,
                                            const float* __restrict__ bMod,
                                            float* __restrict__ out) {
    __shared__ __align__(16) unsigned short sW[5 * 68 * 72];  // 48960 B
    __shared__ float omS[4][27][16];                          // 6912 B
    const int t = threadIdx.x;
    const int lane = t & 63;
    const int wv = t >> 6;
    const int b = blockIdx.x & 7;
    const int yh = blockIdx.x >> 3;
    const int y = yh >> 1;
    const int h = yh & 1;
    const int wx0 = h * 64 - 2;   // window px origin
    const int ylo = y - 2;        // window row origin

    // ---- stage 5x68 window (coalesced global reads, aligned b128 writes) --
    for (int i = t; i < 2720; i += 256) {
        const int c8 = i & 7;
        const int p  = (i >> 3) % 68;
        const int r  = (i >> 3) / 68;
        const int gx = wx0 + p;
        const int gy = ylo + r;
        bf16x8 v = {0, 0, 0, 0, 0, 0, 0, 0};
        if (gx >= 0 && gx < W_ && gy >= 0 && gy < H_)
            v = *(const bf16x8*)&xtb[(((size_t)(b * H_ + gy)) * W_ + gx) * 64 + c8 * 8];
        *(bf16x8*)&sW[(r * 68 + p) * 72 + c8 * 8] = v;
    }
    __syncthreads();

    const int n15 = lane & 15;
    const int q4 = lane >> 4;
    const int px = h * 64 + wv * 16 + n15;

    // ---- Phase 1: 3x3 off/mod conv GEMM from the window ----
    {
        f32x4 accO[2];
        accO[0] = (f32x4){0.f, 0.f, 0.f, 0.f};
        accO[1] = (f32x4){0.f, 0.f, 0.f, 0.f};
#pragma unroll
        for (int kc = 0; kc < 18; ++kc) {
            const int gkb = kc * 32 + q4 * 8;
            const int tap = gkb >> 6;
            const int ci = gkb & 63;
            const int row = tap / 3, kx = tap % 3;
            const bf16x8 bf = *(const bf16x8*)
                &sW[((row + 1) * 68 + (wv * 16 + n15 + kx + 1)) * 72 + ci];
            const bf16x8 a0 = *(const bf16x8*)(wrP2 + (((size_t)(kc * 2 + 0) * 64 + lane) * 8));
            const bf16x8 a1 = *(const bf16x8*)(wrP2 + (((size_t)(kc * 2 + 1) * 64 + lane) * 8));
            accO[0] = __builtin_amdgcn_mfma_f32_16x16x32_bf16(a0, bf, accO[0], 0, 0, 0);
            accO[1] = __builtin_amdgcn_mfma_f32_16x16x32_bf16(a1, bf, accO[1], 0, 0, 0);
        }
#pragma unroll
        for (int mt = 0; mt < 2; ++mt)
#pragma unroll
            for (int r = 0; r < 4; ++r) {
                const int o = mt * 16 + q4 * 4 + r;
                if (o < 18) {
                    const int c = (o >> 1) + ((o & 1) ? 9 : 0);
                    omS[wv][c][n15] = accO[mt][r] + bOff[o];
                } else if (o < 27) {
                    const float z = accO[mt][r] + bMod[o - 18];
                    omS[wv][o][n15] = 2.f / (1.f + __expf(-z));
                }
            }
    }
    __syncthreads();

    // ---- Phase 2: deformable sampling + MFMA einsum ----
    const char* xbB = (const char*)(xtb + (size_t)b * HW_ * 64);

    float omv[27];
#pragma unroll
    for (int i = 0; i < 27; ++i) omv[i] = omS[wv][i][n15];

    f32x4 acc[4];
#pragma unroll
    for (int mt = 0; mt < 4; ++mt) acc[mt] = (f32x4){0.f, 0.f, 0.f, 0.f};

    for (int k = 0; k < 9; ++k) {
        const int ky = k / 3 - 1, kx = k % 3 - 1;
        const float dy  = omv[k];
        const float dxv = omv[9 + k];
        const float m   = omv[18 + k];
        const float py  = (float)(y + ky) + dy;
        const float pxe = (float)(px + kx) + dxv;
        const float y0f = floorf(py), x0f = floorf(pxe);
        const int y0i = (int)y0f, x0i = (int)x0f;
        const float wy1 = py - y0f, wx1 = pxe - x0f;
        const float wy0 = 1.f - wy1, wx0f = 1.f - wx1;

        // ---- shared per-corner weights (identical numerics both paths) ----
        float wts[4];
#pragma unroll
        for (int c = 0; c < 4; ++c) {
            const int cy = c >> 1, cx = c & 1;
            const int yy = y0i + cy;
            const int xx = x0i + cx;
            const bool ok = (yy >= 0) && (yy < H_) && (xx >= 0) && (xx < W_);
            wts[c] = ok ? (cy ? wy1 : wy0) * (cx ? wx1 : wx0f) * m : 0.f;
        }

        // all-4-corners-in-window collapses to one check on the (y0,x0) corner
        const int wr0 = y0i - ylo;
        const int wc0 = x0i - wx0;
        const bool fast = ((unsigned)wr0 <= 3u) && ((unsigned)wc0 <= 66u);

        u32x4 gv[8];
        if (__all(fast)) {
            // ---- fast path: pure LDS, one base + immediate corner offsets --
            const int base = (wr0 * 68 + wc0) * 72 + q4 * 8;
            const bf16x8 l00 = *(const bf16x8*)&sW[base];               // (0,0) lo
            const bf16x8 h00 = *(const bf16x8*)&sW[base + 32];          // (0,0) hi
            const bf16x8 l01 = *(const bf16x8*)&sW[base + 72];          // (0,1)
            const bf16x8 h01 = *(const bf16x8*)&sW[base + 72 + 32];
            const bf16x8 l10 = *(const bf16x8*)&sW[base + 4896];        // (1,0)
            const bf16x8 h10 = *(const bf16x8*)&sW[base + 4896 + 32];
            const bf16x8 l11 = *(const bf16x8*)&sW[base + 4968];        // (1,1)
            const bf16x8 h11 = *(const bf16x8*)&sW[base + 4968 + 32];
            __builtin_memcpy(&gv[0], &l00, 16);
            __builtin_memcpy(&gv[1], &l01, 16);
            __builtin_memcpy(&gv[2], &l10, 16);
            __builtin_memcpy(&gv[3], &l11, 16);
            __builtin_memcpy(&gv[4], &h00, 16);
            __builtin_memcpy(&gv[5], &h01, 16);
            __builtin_memcpy(&gv[6], &h10, 16);
            __builtin_memcpy(&gv[7], &h11, 16);
        } else {
            // ---- slow path: byte-identical r7/r8 proven constructs --------
#pragma unroll
            for (int c = 0; c < 4; ++c) {
                const int cy = c >> 1, cx = c & 1;
                const int yy = y0i + cy;
                const int xx = x0i + cx;
                const bool inw = (yy >= ylo) && (yy <= ylo + 4)
                              && (xx >= wx0) && (xx < wx0 + 68);
                int wr = yy - ylo; wr = min(max(wr, 0), 4);
                int wc = xx - wx0; wc = min(max(wc, 0), 67);
                const int lsW = (wr * 68 + wc) * 72 + q4 * 8;
                const bf16x8 l0 = *(const bf16x8*)&sW[lsW];
                const bf16x8 l1 = *(const bf16x8*)&sW[lsW + 32];
                const int yc = min(max(yy, 0), H_ - 1);
                const int xc = min(max(xx, 0), W_ - 1);
                const int off = inw ? (q4 * 16) : ((yc * W_ + xc) * 128 + q4 * 16);
                const bf16x8 g0 = *(const bf16x8*)(xbB + off);
                const bf16x8 g1 = *(const bf16x8*)(xbB + off + 64);
                u32x4 lu0, lu1, gu0, gu1;
                __builtin_memcpy(&lu0, &l0, 16);
                __builtin_memcpy(&lu1, &l1, 16);
                __builtin_memcpy(&gu0, &g0, 16);
                __builtin_memcpy(&gu1, &g1, 16);
                gv[c]     = sel4(inw, lu0, gu0);
                gv[4 + c] = sel4(inw, lu1, gu1);
            }
        }

        const float w0 = wts[0], w1 = wts[1], w2 = wts[2], w3 = wts[3];
#pragma unroll
        for (int kc = 0; kc < 2; ++kc) {
            unsigned int outw[4];
#pragma unroll
            for (int d = 0; d < 4; ++d) {
                const unsigned int av = gv[kc * 4 + 0][d];
                const unsigned int bv = gv[kc * 4 + 1][d];
                const unsigned int cv = gv[kc * 4 + 2][d];
                const unsigned int ev = gv[kc * 4 + 3][d];
                const float lo = __uint_as_float(av << 16) * w0
                               + __uint_as_float(bv << 16) * w1
                               + __uint_as_float(cv << 16) * w2
                               + __uint_as_float(ev << 16) * w3;
                const float hi = __uint_as_float(av & 0xffff0000u) * w0
                               + __uint_as_float(bv & 0xffff0000u) * w1
                               + __uint_as_float(cv & 0xffff0000u) * w2
                               + __uint_as_float(ev & 0xffff0000u) * w3;
                outw[d] = cvt_pk_bf16(lo, hi);
            }
            const bf16x8 bfB = *(const bf16x8*)outw;
#pragma unroll
            for (int mt = 0; mt < 4; ++mt) {
                const bf16x8 a = *(const bf16x8*)(wrP +
                    ((((size_t)((k * 2 + kc) * 4 + mt)) * 64 + lane) * 8));
                acc[mt] = __builtin_amdgcn_mfma_f32_16x16x32_bf16(a, bfB, acc[mt], 0, 0, 0);
            }
        }
    }

    // epilogue: D[o = mt*16 + q4*4 + r][px], out NCHW
#pragma unroll
    for (int mt = 0; mt < 4; ++mt)
#pragma unroll
        for (int r = 0; r < 4; ++r) {
            const int o = mt * 16 + q4 * 4 + r;
            out[(((size_t)(b * 64 + o)) * H_ + y) * W_ + px] = acc[mt][r];
        }
}

// ---------------------------------------------------------------------------
extern "C" void kernel_launch(void* const* d_in, const int* in_sizes, int n_in,
                              void* d_out, int out_size, void* d_ws, size_t ws_size,
                              hipStream_t stream) {
    const float* x_img  = (const float*)d_in[0];
    const float* x_cont = (const float*)d_in[1];
    const float* w_fuse = (const float*)d_in[2];
    const float* w_off  = (const float*)d_in[3];
    const float* b_off  = (const float*)d_in[4];
    const float* w_mod  = (const float*)d_in[5];
    const float* b_mod  = (const float*)d_in[6];
    const float* w_reg  = (const float*)d_in[7];
    float* out = (float*)d_out;

    float* ws  = (float*)d_ws;
    unsigned short* wrP  = (unsigned short*)(ws + WS_WRP);
    unsigned short* wrP2 = (unsigned short*)(ws + WS_WRP2);
    unsigned short* xtb  = (unsigned short*)(ws + WS_XT);

    k_fuse<<<B_ * H_ * 2, 256, 0, stream>>>(x_img, x_cont, w_fuse, w_reg, w_off,
                                            w_mod, xtb, wrP, wrP2);
    k_od<<<B_ * H_ * 2, 256, 0, stream>>>(xtb, wrP2, wrP, b_off, b_mod, out);
}